// Round 2
// baseline (395.017 us; speedup 1.0000x reference)
//
#include <hip/hip_runtime.h>
#include <hip/hip_fp16.h>

// ---------------- kernels ----------------

__global__ void k_degree(const int* __restrict__ dstA, int* __restrict__ deg, int E) {
  int e = blockIdx.x * blockDim.x + threadIdx.x;
  if (e < E) atomicAdd(&deg[dstA[e]], 1);
}

__global__ void k_scan_a(const int* __restrict__ deg, int* __restrict__ bsum, int N) {
  __shared__ int lds[256];
  int i = blockIdx.x * 256 + threadIdx.x;
  int v = (i < N) ? deg[i] : 0;
  lds[threadIdx.x] = v;
  __syncthreads();
  for (int s = 128; s > 0; s >>= 1) {
    if (threadIdx.x < s) lds[threadIdx.x] += lds[threadIdx.x + s];
    __syncthreads();
  }
  if (threadIdx.x == 0) bsum[blockIdx.x] = lds[0];
}

__global__ void k_scan_b(const int* __restrict__ bsum, int* __restrict__ bsumEx, int nb) {
  __shared__ int lds[1024];
  int t = threadIdx.x;
  int v = (t < nb) ? bsum[t] : 0;
  lds[t] = v;
  __syncthreads();
  for (int d = 1; d < 1024; d <<= 1) {
    int add = (t >= d) ? lds[t - d] : 0;
    __syncthreads();
    lds[t] += add;
    __syncthreads();
  }
  if (t < nb) bsumEx[t] = lds[t] - v;
}

__global__ void k_scan_c(const int* __restrict__ deg, const int* __restrict__ bsumEx,
                         int* __restrict__ offA, int* __restrict__ cursor, int N) {
  __shared__ int lds[256];
  int i = blockIdx.x * 256 + threadIdx.x;
  int v = (i < N) ? deg[i] : 0;
  lds[threadIdx.x] = v;
  __syncthreads();
  for (int d = 1; d < 256; d <<= 1) {
    int add = (threadIdx.x >= d) ? lds[threadIdx.x - d] : 0;
    __syncthreads();
    lds[threadIdx.x] += add;
    __syncthreads();
  }
  int ex = lds[threadIdx.x] - v + bsumEx[blockIdx.x];
  if (i < N) { offA[i] = ex; cursor[i] = ex; }
}

__global__ void k_fill(const int* __restrict__ srcA, const int* __restrict__ dstA,
                       int* __restrict__ cursor, int* __restrict__ csr, int E) {
  int e = blockIdx.x * blockDim.x + threadIdx.x;
  if (e < E) {
    int d = dstA[e];
    int p = atomicAdd(&cursor[d], 1);
    csr[p] = srcA[e];
  }
}

__global__ void k_xhalf(const float4* __restrict__ x4, __half2* __restrict__ xh2, int n4) {
  int i = blockIdx.x * blockDim.x + threadIdx.x;
  if (i < n4) {
    float4 v = x4[i];
    __half2 a, b;
    a.x = __float2half_rn(v.x); a.y = __float2half_rn(v.y);
    b.x = __float2half_rn(v.z); b.y = __float2half_rn(v.w);
    xh2[2 * i] = a;
    xh2[2 * i + 1] = b;
  }
}

// M2 = We_s @ Wn_a, M3 = We_d @ Wn_a, c2 = b_e @ Wn_a
__global__ void k_mats(const float* __restrict__ We, const float* __restrict__ be,
                       const float* __restrict__ Wn, float* __restrict__ M2,
                       float* __restrict__ M3, float* __restrict__ c2) {
  int b = blockIdx.x, t = threadIdx.x;
  if (b < 16) {
    int idx = b * 256 + t; int i = idx >> 6, j = idx & 63;
    float a = 0.f;
    for (int m = 0; m < 64; ++m) a += We[i * 64 + m] * Wn[(64 + m) * 64 + j];
    M2[idx] = a;
  } else if (b < 32) {
    int idx = (b - 16) * 256 + t; int i = idx >> 6, j = idx & 63;
    float a = 0.f;
    for (int m = 0; m < 64; ++m) a += We[(64 + i) * 64 + m] * Wn[(64 + m) * 64 + j];
    M3[idx] = a;
  } else if (t < 64) {
    float a = 0.f;
    for (int m = 0; m < 64; ++m) a += be[m] * Wn[(64 + m) * 64 + t];
    c2[t] = a;
  }
}

// S[n] = sum over incoming edges of x[src] (fp16 gather, fp32 accumulate)
__global__ void k_agg(const __half* __restrict__ xh, const int* __restrict__ offA,
                      const int* __restrict__ deg, const int* __restrict__ csr,
                      float* __restrict__ S, int N) {
  int lane = threadIdx.x & 63;
  int wid = (blockIdx.x * blockDim.x + threadIdx.x) >> 6;
  int nw = (gridDim.x * blockDim.x) >> 6;
  for (int n = wid; n < N; n += nw) {
    int j0 = offA[n], dg = deg[n];
    float acc = 0.f;
    int j = 0;
    for (; j + 4 <= dg; j += 4) {
      int s0 = csr[j0 + j], s1 = csr[j0 + j + 1], s2 = csr[j0 + j + 2], s3 = csr[j0 + j + 3];
      float v0 = __half2float(xh[(size_t)s0 * 64 + lane]);
      float v1 = __half2float(xh[(size_t)s1 * 64 + lane]);
      float v2 = __half2float(xh[(size_t)s2 * 64 + lane]);
      float v3 = __half2float(xh[(size_t)s3 * 64 + lane]);
      acc += v0 + v1 + v2 + v3;
    }
    for (; j < dg; ++j) {
      int s = csr[j0 + j];
      acc += __half2float(xh[(size_t)s * 64 + lane]);
    }
    S[(size_t)n * 64 + lane] = acc;
  }
}

// h = PReLU(x@M1 + S@M2 + deg*(x@M3 + c2) + b_node); h may alias S.
__global__ __launch_bounds__(256) void k_nodeB(
    const float* __restrict__ x, const float* __restrict__ S,
    const int* __restrict__ deg, const float* __restrict__ Wn,
    const float* __restrict__ M2, const float* __restrict__ M3,
    const float* __restrict__ c2, const float* __restrict__ bnode,
    const float* __restrict__ prelu_a, float* __restrict__ h,
    float* __restrict__ stats, int N) {
  __shared__ float l1[4096], l2[4096], l3[4096], lc[64], lb[64];
  int t = threadIdx.x;
  for (int i = t; i < 4096; i += 256) {
    l1[i] = Wn[i];   // M1 = W_node rows 0..63
    l2[i] = M2[i];
    l3[i] = M3[i];
  }
  if (t < 64) { lc[t] = c2[t]; lb[t] = bnode[t]; }
  __syncthreads();
  float slope = prelu_a[0];
  int lane = t & 63;
  int wid = (blockIdx.x * blockDim.x + t) >> 6;
  int nw = (gridDim.x * blockDim.x) >> 6;
  float wsum = 0.f, wsq = 0.f;
  for (int n = wid; n < N; n += nw) {
    float xv = x[(size_t)n * 64 + lane];
    float sv = S[(size_t)n * 64 + lane];
    float dg = (float)deg[n];
    float a1 = 0.f, a2 = 0.f, a3 = 0.f;
#pragma unroll
    for (int k = 0; k < 64; ++k) {
      float xk = __uint_as_float(__builtin_amdgcn_readlane(__float_as_uint(xv), k));
      float sk = __uint_as_float(__builtin_amdgcn_readlane(__float_as_uint(sv), k));
      a1 = fmaf(xk, l1[k * 64 + lane], a1);
      a2 = fmaf(sk, l2[k * 64 + lane], a2);
      a3 = fmaf(xk, l3[k * 64 + lane], a3);
    }
    float hv = a1 + a2 + dg * (a3 + lc[lane]) + lb[lane];
    hv = hv >= 0.f ? hv : slope * hv;
    h[(size_t)n * 64 + lane] = hv;
    wsum += hv;
    wsq += hv * hv;
  }
  atomicAdd(&stats[lane], wsum);
  atomicAdd(&stats[64 + lane], wsq);
}

__global__ void k_bnfinal(const float* __restrict__ stats, const float* __restrict__ gamma,
                          const float* __restrict__ beta, float* __restrict__ ss, int N) {
  int o = threadIdx.x;
  if (o < 64) {
    float fn = (float)N;
    float mean = stats[o] / fn;
    float var = stats[64 + o] / fn - mean * mean;
    float inv = rsqrtf(var + 1e-5f);
    float sc = gamma[o] * inv;
    ss[o] = sc;
    ss[64 + o] = beta[o] - mean * sc;
  }
}

__global__ void k_out(const float4* __restrict__ h4, const float* __restrict__ ss,
                      float4* __restrict__ out4, int n4) {
  int i = blockIdx.x * blockDim.x + threadIdx.x;
  if (i < n4) {
    int c4 = (i & 15) * 4;
    float4 v = h4[i];
    float4 sc = *(const float4*)(ss + c4);
    float4 sh = *(const float4*)(ss + 64 + c4);
    float4 o;
    o.x = v.x * sc.x + sh.x;
    o.y = v.y * sc.y + sh.y;
    o.z = v.z * sc.z + sh.z;
    o.w = v.w * sc.w + sh.w;
    out4[i] = o;
  }
}

// ---------------- launch ----------------

extern "C" void kernel_launch(void* const* d_in, const int* in_sizes, int n_in,
                              void* d_out, int out_size, void* d_ws, size_t ws_size,
                              hipStream_t stream) {
  const float* x     = (const float*)d_in[0];
  const int*   ei    = (const int*)d_in[1];
  const float* We    = (const float*)d_in[2];
  const float* be    = (const float*)d_in[3];
  const float* Wn    = (const float*)d_in[4];
  const float* bnode = (const float*)d_in[5];
  const float* pa    = (const float*)d_in[6];
  const float* gamma = (const float*)d_in[7];
  const float* beta  = (const float*)d_in[8];

  int N = in_sizes[0] / 64;
  int E = in_sizes[1] / 2;
  const int* srcA = ei;
  const int* dstA = ei + E;

  char* ws = (char*)d_ws;
  size_t off = 0;
  auto alloc = [&](size_t bytes) -> void* {
    void* p = (void*)(ws + off);
    off += (bytes + 255) & ~(size_t)255;
    return p;
  };
  int*    deg    = (int*)alloc((size_t)N * 4);
  int*    offA   = (int*)alloc((size_t)N * 4);
  int*    cursor = (int*)alloc((size_t)N * 4);
  int*    bsum   = (int*)alloc(1024 * 4);
  int*    bsumEx = (int*)alloc(1024 * 4);
  int*    csr    = (int*)alloc((size_t)E * 4);
  __half* xh     = (__half*)alloc((size_t)N * 64 * 2);
  float*  S      = (float*)alloc((size_t)N * 64 * 4);  // h aliases S
  float*  M2     = (float*)alloc(4096 * 4);
  float*  M3     = (float*)alloc(4096 * 4);
  float*  c2     = (float*)alloc(64 * 4);
  float*  stats  = (float*)alloc(128 * 4);
  float*  ssbuf  = (float*)alloc(128 * 4);
  float*  h      = S;  // alias: each wave reads its own S row before writing h row

  hipMemsetAsync(deg, 0, (size_t)N * 4, stream);
  hipMemsetAsync(stats, 0, 128 * 4, stream);

  int NB = (N + 255) / 256;
  int egrid = (E + 255) / 256;
  int n4 = N * 16;
  int vgrid = (n4 + 255) / 256;

  k_degree<<<egrid, 256, 0, stream>>>(dstA, deg, E);
  k_scan_a<<<NB, 256, 0, stream>>>(deg, bsum, N);
  k_scan_b<<<1, 1024, 0, stream>>>(bsum, bsumEx, NB);
  k_scan_c<<<NB, 256, 0, stream>>>(deg, bsumEx, offA, cursor, N);
  k_fill<<<egrid, 256, 0, stream>>>(srcA, dstA, cursor, csr, E);
  k_xhalf<<<vgrid, 256, 0, stream>>>((const float4*)x, (__half2*)xh, n4);
  k_mats<<<33, 256, 0, stream>>>(We, be, Wn, M2, M3, c2);
  k_agg<<<2048, 256, 0, stream>>>(xh, offA, deg, csr, S, N);
  k_nodeB<<<768, 256, 0, stream>>>(x, S, deg, Wn, M2, M3, c2, bnode, pa, h, stats, N);
  k_bnfinal<<<1, 64, 0, stream>>>(stats, gamma, beta, ssbuf, N);
  k_out<<<vgrid, 256, 0, stream>>>((const float4*)h, ssbuf, (float4*)d_out, n4);
}